// Round 1
// baseline (1683.735 us; speedup 1.0000x reference)
//
#include <hip/hip_runtime.h>

#define NS 50000
#define NP 50048   // 782*64 padded rows
#define NG 2000
#define KP 2048    // padded K / N for the 2000-dims
#define NE 800000

typedef float f32x4 __attribute__((ext_vector_type(4)));
typedef __bf16 bf16x8 __attribute__((ext_vector_type(8)));
typedef short s4v __attribute__((ext_vector_type(4)));
typedef short s8v __attribute__((ext_vector_type(8)));

#define AMFMA(a,b,c) __builtin_amdgcn_mfma_f32_16x16x32_bf16((a),(b),(c),0,0,0)

__device__ __forceinline__ short f2bs(float f){
  unsigned u = __builtin_bit_cast(unsigned, f);
  u = (u + 0x7FFFu + ((u >> 16) & 1u)) >> 16;   // RNE
  return (short)u;
}
__device__ __forceinline__ float bs2f(short s){
  unsigned u = ((unsigned)(unsigned short)s) << 16;
  return __builtin_bit_cast(float, u);
}

// ---------------- weight pre-transpose + bf16 convert ----------------
// Layouts: WT[n][k] (k-contiguous) so B-fragments read 8 contiguous bf16.
__global__ void k_prep(const float* __restrict__ W1, const float* __restrict__ W2,
    const float* __restrict__ Wp1, const float* __restrict__ Wp2, const float* __restrict__ Ws1,
    const float* __restrict__ We1, const float* __restrict__ Ws2, const float* __restrict__ We2,
    short* __restrict__ W1T, short* __restrict__ W2T, short* __restrict__ Wp1T,
    short* __restrict__ Wp2T, short* __restrict__ Ws1T, short* __restrict__ We1T,
    short* __restrict__ Ws2T, short* __restrict__ We2T){
  int id = blockIdx.x*256 + threadIdx.x;
  if (id < 64*KP){ int n=id/KP, k=id%KP; W1T[id] = (k<NG) ? f2bs(W1[(long)k*64+n]) : (short)0; return; }
  id -= 64*KP;
  if (id < 4096){ int n=id>>6, k=id&63; W2T[id]=f2bs(W2[k*64+n]); return; } id-=4096;
  if (id < 4096){ int n=id>>6, k=id&63; Wp1T[id]=f2bs(Wp1[k*64+n]); return; } id-=4096;
  if (id < 4096){ int n=id>>6, k=id&63; Ws1T[id]=f2bs(Ws1[k*64+n]); return; } id-=4096;
  if (id < 4096){ int n=id>>6, k=id&63; We1T[id]=f2bs(We1[k*64+n]); return; } id-=4096;
  if (id < 1024){ int n=id>>6, k=id&63; Wp2T[id]=(n<2)?f2bs(Wp2[k*2+n]):(short)0; return; } id-=1024;
  if (id < 131072){ int n=id>>6, k=id&63; Ws2T[id]=(n<NG)?f2bs(Ws2[(long)k*NG+n]):(short)0; return; } id-=131072;
  if (id < 131072){ int n=id>>6, k=id&63; We2T[id]=(n<NG)?f2bs(We2[(long)k*NG+n]):(short)0; }
}

// ---------------- GEMM1: z = x @ W1 + b1, f32 out + BN stats ----------------
__global__ __launch_bounds__(256) void k_gemm1(const float* __restrict__ x,
    const float* __restrict__ b1, const short* __restrict__ W1T,
    float* __restrict__ zbuf, float* __restrict__ stats){
  __shared__ __align__(16) short xa[64*72];  // stride 72 shorts = 36 dwords -> 2-way (free)
  __shared__ __align__(16) short wb[64*72];
  __shared__ float sred[512];
  const int t=threadIdx.x, wave=t>>6, lane=t&63;
  const int r=lane&15, q=lane>>4;
  const int r0=blockIdx.x*64;
  f32x4 acc[4] = {};
  for (int k0=0; k0<KP; k0+=64){
    __syncthreads();
    #pragma unroll
    for (int j=0;j<4;j++){                 // stage x tile 64x64 f32 -> bf16
      int cid=t+j*256; int row=cid>>4, kc=(cid&15)*4;
      int gr=r0+row, gk=k0+kc;
      float4 v = {0.f,0.f,0.f,0.f};
      if (gr<NS && gk<NG) v = *(const float4*)(x + (long)gr*NG + gk);
      const float* vp=(const float*)&v;
      s4v sv;
      #pragma unroll
      for (int i=0;i<4;i++) sv[i]=f2bs(vp[i]);
      *(s4v*)&xa[row*72+kc]=sv;
    }
    #pragma unroll
    for (int j=0;j<2;j++){                 // stage W1T chunk (already bf16)
      int cid=t+j*256; int n=cid>>3, kk=(cid&7)*8;
      *(int4*)&wb[n*72+kk] = *(const int4*)&W1T[n*KP + k0 + kk];
    }
    __syncthreads();
    #pragma unroll
    for (int h=0;h<2;h++){
      bf16x8 a = *(const bf16x8*)&xa[(wave*16+r)*72 + h*32 + q*8];
      #pragma unroll
      for (int nt=0;nt<4;nt++){
        bf16x8 b = *(const bf16x8*)&wb[(nt*16+r)*72 + h*32 + q*8];
        acc[nt]=AMFMA(a,b,acc[nt]);
      }
    }
  }
  float s1[4], s2[4];
  #pragma unroll
  for (int nt=0;nt<4;nt++){
    int col=nt*16+r; float bias=b1[col];
    s1[nt]=0.f; s2[nt]=0.f;
    #pragma unroll
    for (int i=0;i<4;i++){
      int row=wave*16+q*4+i; int gr=r0+row;
      float z=acc[nt][i]+bias;
      zbuf[(long)(r0+row)*64+col]=z;
      if (gr<NS){ s1[nt]+=z; s2[nt]+=z*z; }
    }
  }
  #pragma unroll
  for (int nt=0;nt<4;nt++){
    s1[nt]+=__shfl_xor(s1[nt],16); s1[nt]+=__shfl_xor(s1[nt],32);
    s2[nt]+=__shfl_xor(s2[nt],16); s2[nt]+=__shfl_xor(s2[nt],32);
  }
  if (q==0){
    #pragma unroll
    for (int nt=0;nt<4;nt++){
      sred[wave*128 + nt*16 + r]      = s1[nt];
      sred[wave*128 + 64 + nt*16 + r] = s2[nt];
    }
  }
  __syncthreads();
  if (t<128){
    float v = sred[t]+sred[128+t]+sred[256+t]+sred[384+t];
    atomicAdd(&stats[t], v);
  }
}

__global__ void k_bnparam(const float* __restrict__ stats, const float* __restrict__ gamma,
                          const float* __restrict__ beta, float* __restrict__ ab){
  int c=threadIdx.x;
  float mean = stats[c]*(1.0f/NS);
  float var  = stats[64+c]*(1.0f/NS) - mean*mean;
  float a = gamma[c]*rsqrtf(var + 1e-5f);
  ab[c]=a; ab[64+c]=beta[c]-mean*a;
}

// ---------------- fused: BN+ReLU -> h -> {pos head, hs} ----------------
__global__ __launch_bounds__(256) void k_fused(const float* __restrict__ zbuf,
    const float* __restrict__ ab, const float* __restrict__ b2, const float* __restrict__ bp1,
    const float* __restrict__ bp2, const float* __restrict__ bs1,
    const short* __restrict__ W2T, const short* __restrict__ Wp1T,
    const short* __restrict__ Wp2T, const short* __restrict__ Ws1T,
    float* __restrict__ out_h, float* __restrict__ out_pos,
    short* __restrict__ hbuf, short* __restrict__ hsbuf){
  __shared__ __align__(16) short tb[64*72];
  __shared__ __align__(16) short w2[64*72];
  __shared__ __align__(16) short wp[64*72];
  __shared__ __align__(16) short ws1s[64*72];
  __shared__ __align__(16) short wp2s[16*72];
  const int t=threadIdx.x, wave=t>>6, lane=t&63;
  const int r=lane&15, q=lane>>4;
  const int r0=blockIdx.x*64;
  #pragma unroll
  for (int j=0;j<2;j++){
    int cid=t+j*256; int n=cid>>3, kk=(cid&7)*8;
    *(int4*)&w2[n*72+kk]   = *(const int4*)&W2T[n*64+kk];
    *(int4*)&wp[n*72+kk]   = *(const int4*)&Wp1T[n*64+kk];
    *(int4*)&ws1s[n*72+kk] = *(const int4*)&Ws1T[n*64+kk];
  }
  if (t<128){ int n=t>>3, kk=(t&7)*8; *(int4*)&wp2s[n*72+kk]=*(const int4*)&Wp2T[n*64+kk]; }
  #pragma unroll
  for (int j=0;j<4;j++){                    // z tile + BN + ReLU -> bf16
    int cid=t+j*256; int row=cid>>4, kc=(cid&15)*4;
    float4 v=*(const float4*)(zbuf + (long)(r0+row)*64 + kc);
    const float* vp=(const float*)&v;
    s4v sv;
    #pragma unroll
    for (int i=0;i<4;i++){
      int c=kc+i;
      sv[i]=f2bs(fmaxf(vp[i]*ab[c]+ab[64+c], 0.f));
    }
    *(s4v*)&tb[row*72+kc]=sv;
  }
  __syncthreads();
  f32x4 hacc[4]={};
  {
    bf16x8 a0=*(const bf16x8*)&tb[(wave*16+r)*72+q*8];
    bf16x8 a1=*(const bf16x8*)&tb[(wave*16+r)*72+32+q*8];
    #pragma unroll
    for (int nt=0;nt<4;nt++){
      bf16x8 b0=*(const bf16x8*)&w2[(nt*16+r)*72+q*8];
      bf16x8 b1=*(const bf16x8*)&w2[(nt*16+r)*72+32+q*8];
      hacc[nt]=AMFMA(a0,b0,hacc[nt]); hacc[nt]=AMFMA(a1,b1,hacc[nt]);
    }
  }
  short hsv[4][4];
  #pragma unroll
  for (int nt=0;nt<4;nt++){
    int col=nt*16+r; float bias=b2[col];
    #pragma unroll
    for (int i=0;i<4;i++){
      int row=wave*16+q*4+i; int gr=r0+row;
      float h=hacc[nt][i]+bias;
      short hb=f2bs(h); hsv[nt][i]=hb;
      if (gr<NS) out_h[(long)gr*64+col]=h;
      hbuf[(long)(r0+row)*64+col]=hb;
    }
  }
  __syncthreads();
  #pragma unroll
  for (int nt=0;nt<4;nt++)
    #pragma unroll
    for (int i=0;i<4;i++)
      tb[(wave*16+q*4+i)*72 + nt*16+r]=hsv[nt][i];
  __syncthreads();
  f32x4 pacc[4]={}, sacc[4]={};
  {
    bf16x8 a0=*(const bf16x8*)&tb[(wave*16+r)*72+q*8];
    bf16x8 a1=*(const bf16x8*)&tb[(wave*16+r)*72+32+q*8];
    #pragma unroll
    for (int nt=0;nt<4;nt++){
      bf16x8 b0=*(const bf16x8*)&wp[(nt*16+r)*72+q*8];
      bf16x8 b1=*(const bf16x8*)&wp[(nt*16+r)*72+32+q*8];
      pacc[nt]=AMFMA(a0,b0,pacc[nt]); pacc[nt]=AMFMA(a1,b1,pacc[nt]);
      bf16x8 c0=*(const bf16x8*)&ws1s[(nt*16+r)*72+q*8];
      bf16x8 c1=*(const bf16x8*)&ws1s[(nt*16+r)*72+32+q*8];
      sacc[nt]=AMFMA(a0,c0,sacc[nt]); sacc[nt]=AMFMA(a1,c1,sacc[nt]);
    }
  }
  short psv[4][4];
  #pragma unroll
  for (int nt=0;nt<4;nt++){
    int col=nt*16+r; float biasp=bp1[col], biass=bs1[col];
    #pragma unroll
    for (int i=0;i<4;i++){
      int row=wave*16+q*4+i;
      psv[nt][i]=f2bs(fmaxf(pacc[nt][i]+biasp,0.f));
      hsbuf[(long)(r0+row)*64+col]=f2bs(fmaxf(sacc[nt][i]+biass,0.f));
    }
  }
  __syncthreads();
  #pragma unroll
  for (int nt=0;nt<4;nt++)
    #pragma unroll
    for (int i=0;i<4;i++)
      tb[(wave*16+q*4+i)*72 + nt*16+r]=psv[nt][i];
  __syncthreads();
  f32x4 poacc={};
  {
    bf16x8 a0=*(const bf16x8*)&tb[(wave*16+r)*72+q*8];
    bf16x8 a1=*(const bf16x8*)&tb[(wave*16+r)*72+32+q*8];
    bf16x8 b0=*(const bf16x8*)&wp2s[r*72+q*8];
    bf16x8 b1=*(const bf16x8*)&wp2s[r*72+32+q*8];
    poacc=AMFMA(a0,b0,poacc); poacc=AMFMA(a1,b1,poacc);
  }
  if (r<2){
    float bias=bp2[r];
    #pragma unroll
    for (int i=0;i<4;i++){
      int gr=r0+wave*16+q*4+i;
      if (gr<NS) out_pos[(long)gr*2+r]=poacc[i]+bias;
    }
  }
}

// ---------------- CSR build ----------------
__global__ void k_hist(const int* __restrict__ ei, int* __restrict__ cnt){
  int e=blockIdx.x*256+threadIdx.x;
  if (e<NE) atomicAdd(&cnt[ei[NE+e]], 1);
}
__global__ void k_scan1(const int* __restrict__ cnt, int* __restrict__ bsum){
  const int t=threadIdx.x, lane=t&63, wave=t>>6;
  const int base=blockIdx.x*1024;
  int4 v=*(const int4*)&cnt[base+t*4];     // cnt padded+zeroed to 50176
  int s=v.x+v.y+v.z+v.w;
  #pragma unroll
  for (int o=1;o<64;o<<=1) s+=__shfl_xor(s,o);
  __shared__ int wsm[4];
  if (lane==0) wsm[wave]=s;
  __syncthreads();
  if (t==0) bsum[blockIdx.x]=wsm[0]+wsm[1]+wsm[2]+wsm[3];
}
__global__ void k_scan2(const int* __restrict__ bsum, int* __restrict__ boff){
  if (threadIdx.x==0){ int s=0; for (int i=0;i<49;i++){ boff[i]=s; s+=bsum[i]; } }
}
__global__ void k_scan3(const int* __restrict__ cnt, const int* __restrict__ boff,
                        int* __restrict__ offv, int* __restrict__ cur){
  const int t=threadIdx.x, lane=t&63, wave=t>>6;
  const int base=blockIdx.x*1024;
  int4 v=*(const int4*)&cnt[base+t*4];
  int e1=v.x, e2=v.x+v.y, e3=e2+v.z;
  int ts=e3+v.w;
  int incl=ts;
  #pragma unroll
  for (int o=1;o<64;o<<=1){ int n=__shfl_up(incl,o); if (lane>=o) incl+=n; }
  int wexcl=incl-ts;
  __shared__ int wsm[4];
  if (lane==63) wsm[wave]=incl;
  __syncthreads();
  int woff=0;
  #pragma unroll
  for (int w=0;w<4;w++) if (w<wave) woff+=wsm[w];
  int tex=wexcl+woff+boff[blockIdx.x];
  int4 o4; o4.x=tex; o4.y=tex+e1; o4.z=tex+e2; o4.w=tex+e3;
  int idx=base+t*4;
  *(int4*)&offv[idx]=o4;   // buffers padded to 50176
  *(int4*)&cur[idx]=o4;
}
__global__ void k_scatter(const int* __restrict__ ei, int* __restrict__ cur, int* __restrict__ srcl){
  int e=blockIdx.x*256+threadIdx.x;
  if (e<NE){
    int s=ei[e], d=ei[NE+e];
    int p=atomicAdd(&cur[d],1);
    srcl[p]=s;
  }
}

// ---------------- big decoder GEMM: out = in[NPx64] @ WT^T + bias ----------------
__global__ __launch_bounds__(256) void k_big(const short* __restrict__ inbuf,
    const short* __restrict__ WT, const float* __restrict__ bias2, float* __restrict__ outp){
  __shared__ __align__(16) short tb[64*72];
  const int t=threadIdx.x, wave=t>>6, lane=t&63;
  const int r=lane&15, q=lane>>4;
  const int r0=blockIdx.x*64;
  #pragma unroll
  for (int j=0;j<2;j++){
    int cid=t+j*256; int row=cid>>3, kk=(cid&7)*8;
    *(int4*)&tb[row*72+kk]=*(const int4*)&inbuf[(long)(r0+row)*64+kk];
  }
  __syncthreads();
  bf16x8 a0=*(const bf16x8*)&tb[(wave*16+r)*72+q*8];
  bf16x8 a1=*(const bf16x8*)&tb[(wave*16+r)*72+32+q*8];
  const int rowbase=r0+wave*16+q*4;
  for (int n0=0;n0<KP;n0+=64){
    #pragma unroll
    for (int nt=0;nt<4;nt++){
      int col=n0+nt*16+r;
      bf16x8 b0=*(const bf16x8*)&WT[(long)col*64+q*8];
      bf16x8 b1=*(const bf16x8*)&WT[(long)col*64+32+q*8];
      f32x4 acc={};
      acc=AMFMA(a0,b0,acc); acc=AMFMA(a1,b1,acc);
      if (col<NG){
        float bias=bias2[col];
        #pragma unroll
        for (int i=0;i<4;i++){
          int gr=rowbase+i;
          if (gr<NS) outp[(long)gr*NG+col]=acc[i]+bias;
        }
      }
    }
  }
}

// ---------------- gather h_agg + We1 stage + big GEMM ----------------
__global__ __launch_bounds__(256) void k_neigh(const short* __restrict__ hbuf,
    const int* __restrict__ cnt, const int* __restrict__ offv, const int* __restrict__ srcl,
    const short* __restrict__ We1T, const float* __restrict__ be1,
    const short* __restrict__ We2T, const float* __restrict__ be2, float* __restrict__ outp){
  __shared__ __align__(16) short tb[64*72];
  __shared__ __align__(16) short w1[64*72];
  const int t=threadIdx.x, wave=t>>6, lane=t&63;
  const int r=lane&15, q=lane>>4;
  const int r0=blockIdx.x*64;
  #pragma unroll
  for (int j=0;j<2;j++){
    int cid=t+j*256; int n=cid>>3, kk=(cid&7)*8;
    *(int4*)&w1[n*72+kk]=*(const int4*)&We1T[n*64+kk];
  }
  {
    int row=t>>2, fb=(t&3)*16;
    int gr=r0+row;
    float fa[16];
    #pragma unroll
    for (int i=0;i<16;i++) fa[i]=0.f;
    int d=0;
    if (gr<NS){
      d=cnt[gr]; int o=offv[gr];
      for (int e=0;e<d;e++){
        int s=srcl[o+e];
        const s8v* hp=(const s8v*)&hbuf[(long)s*64+fb];
        s8v v0=hp[0], v1=hp[1];
        #pragma unroll
        for (int i=0;i<8;i++){ fa[i]+=bs2f(v0[i]); fa[8+i]+=bs2f(v1[i]); }
      }
    }
    float inv=1.0f/(float)(d>1?d:1);
    #pragma unroll
    for (int j2=0;j2<4;j2++){
      s4v sv;
      #pragma unroll
      for (int i=0;i<4;i++) sv[i]=f2bs(fa[j2*4+i]*inv);
      *(s4v*)&tb[row*72+fb+j2*4]=sv;
    }
  }
  __syncthreads();
  f32x4 racc[4]={};
  {
    bf16x8 a0=*(const bf16x8*)&tb[(wave*16+r)*72+q*8];
    bf16x8 a1=*(const bf16x8*)&tb[(wave*16+r)*72+32+q*8];
    #pragma unroll
    for (int nt=0;nt<4;nt++){
      bf16x8 b0=*(const bf16x8*)&w1[(nt*16+r)*72+q*8];
      bf16x8 b1=*(const bf16x8*)&w1[(nt*16+r)*72+32+q*8];
      racc[nt]=AMFMA(a0,b0,racc[nt]); racc[nt]=AMFMA(a1,b1,racc[nt]);
    }
  }
  short rsv[4][4];
  #pragma unroll
  for (int nt=0;nt<4;nt++){
    float bias=be1[nt*16+r];
    #pragma unroll
    for (int i=0;i<4;i++) rsv[nt][i]=f2bs(fmaxf(racc[nt][i]+bias,0.f));
  }
  __syncthreads();
  #pragma unroll
  for (int nt=0;nt<4;nt++)
    #pragma unroll
    for (int i=0;i<4;i++)
      tb[(wave*16+q*4+i)*72+nt*16+r]=rsv[nt][i];
  __syncthreads();
  bf16x8 a0=*(const bf16x8*)&tb[(wave*16+r)*72+q*8];
  bf16x8 a1=*(const bf16x8*)&tb[(wave*16+r)*72+32+q*8];
  const int rowbase=r0+wave*16+q*4;
  for (int n0=0;n0<KP;n0+=64){
    #pragma unroll
    for (int nt=0;nt<4;nt++){
      int col=n0+nt*16+r;
      bf16x8 b0=*(const bf16x8*)&We2T[(long)col*64+q*8];
      bf16x8 b1=*(const bf16x8*)&We2T[(long)col*64+32+q*8];
      f32x4 acc={};
      acc=AMFMA(a0,b0,acc); acc=AMFMA(a1,b1,acc);
      if (col<NG){
        float bias=be2[col];
        #pragma unroll
        for (int i=0;i<4;i++){
          int gr=rowbase+i;
          if (gr<NS) outp[(long)gr*NG+col]=acc[i]+bias;
        }
      }
    }
  }
}

extern "C" void kernel_launch(void* const* d_in, const int* in_sizes, int n_in,
                              void* d_out, int out_size, void* d_ws, size_t ws_size,
                              hipStream_t stream){
  const float* x    =(const float*)d_in[0];
  const int*   ei   =(const int*)d_in[1];
  const float* W1   =(const float*)d_in[2];
  const float* b1   =(const float*)d_in[3];
  const float* gamma=(const float*)d_in[4];
  const float* beta =(const float*)d_in[5];
  const float* W2   =(const float*)d_in[6];  const float* b2 =(const float*)d_in[7];
  const float* Wp1  =(const float*)d_in[8];  const float* bp1=(const float*)d_in[9];
  const float* Wp2  =(const float*)d_in[10]; const float* bp2=(const float*)d_in[11];
  const float* Ws1  =(const float*)d_in[12]; const float* bs1=(const float*)d_in[13];
  const float* Ws2  =(const float*)d_in[14]; const float* bs2=(const float*)d_in[15];
  const float* We1  =(const float*)d_in[16]; const float* be1=(const float*)d_in[17];
  const float* We2  =(const float*)d_in[18]; const float* be2=(const float*)d_in[19];

  char* wsb=(char*)d_ws;
  float* stats=(float*)(wsb+0);            // 512
  float* ab   =(float*)(wsb+512);          // 512
  short* W1T  =(short*)(wsb+1024);         // 64*2048*2 = 262144
  short* W2T  =(short*)(wsb+263168);       // 8192
  short* Wp1T =(short*)(wsb+271360);       // 8192
  short* Ws1T =(short*)(wsb+279552);       // 8192
  short* We1T =(short*)(wsb+287744);       // 8192
  short* Wp2T =(short*)(wsb+295936);       // 2048
  short* Ws2T =(short*)(wsb+297984);       // 262144
  short* We2T =(short*)(wsb+560128);       // 262144
  float* zbuf =(float*)(wsb+822272);       // 50048*64*4 = 12812288
  short* hbuf =(short*)(wsb+13634560);     // 6406144
  short* hsbuf=(short*)(wsb+20040704);     // 6406144
  int*   cnt  =(int*)(wsb+26446848);       // 200704 (padded to 50176 ints)
  int*   offv =(int*)(wsb+26647552);       // 200704
  int*   cur  =(int*)(wsb+26848256);       // 200704
  int*   srcl =(int*)(wsb+27048960);       // 3200000
  int*   bsum =(int*)(wsb+30248960);       // 256
  int*   boff =(int*)(wsb+30249216);       // 256

  float* out_h    =(float*)d_out;
  float* out_pos  =out_h   + (long)NS*64;
  float* out_self =out_pos + (long)NS*2;
  float* out_neigh=out_self+ (long)NS*NG;

  hipMemsetAsync(stats, 0, 512, stream);
  hipMemsetAsync(cnt,   0, 200704, stream);

  k_prep<<<1604,256,0,stream>>>(W1,W2,Wp1,Wp2,Ws1,We1,Ws2,We2,
                                W1T,W2T,Wp1T,Wp2T,Ws1T,We1T,Ws2T,We2T);
  k_gemm1<<<782,256,0,stream>>>(x,b1,W1T,zbuf,stats);
  k_bnparam<<<1,64,0,stream>>>(stats,gamma,beta,ab);
  k_fused<<<782,256,0,stream>>>(zbuf,ab,b2,bp1,bp2,bs1,W2T,Wp1T,Wp2T,Ws1T,
                                out_h,out_pos,hbuf,hsbuf);
  k_hist<<<3125,256,0,stream>>>(ei,cnt);
  k_scan1<<<49,256,0,stream>>>(cnt,bsum);
  k_scan2<<<1,64,0,stream>>>(bsum,boff);
  k_scan3<<<49,256,0,stream>>>(cnt,boff,offv,cur);
  k_scatter<<<3125,256,0,stream>>>(ei,cur,srcl);
  k_big<<<782,256,0,stream>>>(hsbuf,Ws2T,bs2,out_self);
  k_neigh<<<782,256,0,stream>>>(hbuf,cnt,offv,srcl,We1T,be1,We2T,be2,out_neigh);
}